// Round 19
// baseline (553.623 us; speedup 1.0000x reference)
//
#include <hip/hip_runtime.h>

// ---------------------------------------------------------------------------
// Sparse 3D U-Net forward (MI355X / gfx950).
// L0 (11% dense): sparse slot lists + amap gather (MFMA implicit GEMM).
// L1/L2 (62%/~100% dense): DENSE voxel-indexed activations; tap addresses
// computed (no amap in the load chain); inactive voxels hold exact 0
// (masked epilogue writes) preserving reference mask semantics.
// All convs = barrier-free mfma_f32_32x32x16_f16, one wave per block,
// CTILES=2 where COUT>=64. BN+ReLU(+f16) fused into producer epilogues.
// A: row=lane&31, k=(lane>>5)*8+j; B: col=lane&31, same k map.
// D: col=lane&31, row=(reg&3)+8*(reg>>2)+4*(lane>>5).
// ---------------------------------------------------------------------------

#define NVOX 100
#define EPSB 1e-4f
typedef unsigned long long u64;
typedef _Float16 h2 __attribute__((ext_vector_type(2)));
typedef _Float16 h8 __attribute__((ext_vector_type(8)));
typedef float f16v __attribute__((ext_vector_type(16)));
#define DEVFN __device__ __forceinline__

DEVFN float bnr(float v, float sc, float sh) { return fmaxf(fmaf(v, sc, sh), 0.f); }

// Packed B: wb[((t*CTG + ctg)*KCH + kc)*256 + lane*4 + jh] (h2 units):
//   k0 = kc*16 + (lane>>5)*8 + 2*jh ; co = ctg*32 + (lane&31)
template<int NTAPS, int CTOT, int COUT>
__global__ __launch_bounds__(256)
void prepB32(const float* __restrict__ w, h2* __restrict__ out)
{
    constexpr int CTG = COUT / 32, KCH = CTOT / 16;
    const int n = NTAPS * CTG * KCH * 256;
    const int idx = blockIdx.x * 256 + threadIdx.x;
    if (idx >= n) return;
    const int jh = idx & 3;
    const int lane = (idx >> 2) & 63;
    int r = idx >> 8;
    const int kc = r % KCH; r /= KCH;
    const int ct = r % CTG; const int t = r / CTG;
    const int k0 = kc * 16 + (lane >> 5) * 8 + 2 * jh;
    const int co = ct * 32 + (lane & 31);
    h2 v;
    v[0] = (_Float16)w[((size_t)t * CTOT + k0) * COUT + co];
    v[1] = (_Float16)w[((size_t)t * CTOT + k0 + 1) * COUT + co];
    out[idx] = v;
}

// 3x3x3 SAME conv, f16 acts, 1-wave blocks. DENSE: tap addr computed, mask
// via ballot(amap[v]>=0), inactive outputs written 0. Sparse: amap lookup.
// EMODE: 0 plain f32; 1 f16 bnrelu; 2 two f16 bnrelu outs.
template<int KC1, int KC2, int CTILES, int COUT, int S, int EMODE, bool DENSE>
__global__ __launch_bounds__(64)
void gconv_m32(const h2* __restrict__ inA, const h2* __restrict__ inB,
               const h2* __restrict__ wb,
               const int* __restrict__ amap, const int* __restrict__ vlist,
               const int* __restrict__ cnt, int cap, int nbx,
               float* __restrict__ outF, _Float16* __restrict__ o1,
               const float* __restrict__ sc1, const float* __restrict__ sh1,
               _Float16* __restrict__ o2,
               const float* __restrict__ sc2, const float* __restrict__ sh2)
{
    constexpr int KCH = KC1 + KC2;
    constexpr int CTG = COUT / 32;
    const int lane = threadIdx.x;
    const int cntv = DENSE ? S * S * S : *cnt;
    const int sid = blockIdx.x;
    const int ct0 = sid / nbx;
    const int wbase = (sid - ct0 * nbx) * 32;
    if (wbase >= cntv) return;
    const int l31 = lane & 31, ksub = lane >> 5;
    const int slot = wbase + l31;
    const bool on = slot < cntv;
    int X = 0, Y = 0, Z = 0;
    if (on) {
        const int v = DENSE ? slot : vlist[slot];
        X = v % S; const int r = v / S; Y = r % S; Z = r / S;
    }
    u64 bal = 0;
    if constexpr (DENSE) bal = __ballot(on && amap[slot] >= 0);

    auto calc_ns = [&](int t) -> int {
        int ns = cap;
        if (on) {
            const int dz = t / 9 - 1, dy = (t / 3) % 3 - 1, dx = t % 3 - 1;
            const int nz = Z + dz, ny = Y + dy, nx = X + dx;
            if ((unsigned)nz < (unsigned)S && (unsigned)ny < (unsigned)S &&
                (unsigned)nx < (unsigned)S) {
                if constexpr (DENSE) {
                    ns = (nz * S + ny) * S + nx;
                } else {
                    const int m = amap[(nz * S + ny) * S + nx];
                    if (m >= 0) ns = m;
                }
            }
        }
        return ns;
    };

    f16v acc[CTILES];
#pragma unroll
    for (int c = 0; c < CTILES; ++c) acc[c] = (f16v)(0.f);
    int ns = calc_ns(0);
#pragma unroll 1
    for (int t = 0; t < 27; ++t) {
        const int ns_nxt = (t + 1 < 27) ? calc_ns(t + 1) : cap;
        const h2* __restrict__ wt =
            wb + ((size_t)t * CTG + ct0 * CTILES) * KCH * 256;
#pragma unroll
        for (int kc = 0; kc < KC1; ++kc) {
            const h8 a = *reinterpret_cast<const h8*>(
                inA + (size_t)ns * (KC1 * 8) + kc * 8 + ksub * 4);
#pragma unroll
            for (int ct = 0; ct < CTILES; ++ct) {
                const h8 b = *reinterpret_cast<const h8*>(
                    wt + ((size_t)ct * KCH + kc) * 256 + lane * 4);
                acc[ct] = __builtin_amdgcn_mfma_f32_32x32x16_f16(a, b, acc[ct], 0, 0, 0);
            }
        }
        if constexpr (KC2 > 0) {
#pragma unroll
            for (int kc = 0; kc < KC2; ++kc) {
                const h8 a = *reinterpret_cast<const h8*>(
                    inB + (size_t)ns * (KC2 * 8) + kc * 8 + ksub * 4);
#pragma unroll
                for (int ct = 0; ct < CTILES; ++ct) {
                    const h8 b = *reinterpret_cast<const h8*>(
                        wt + ((size_t)ct * KCH + KC1 + kc) * 256 + lane * 4);
                    acc[ct] = __builtin_amdgcn_mfma_f32_32x32x16_f16(a, b, acc[ct], 0, 0, 0);
                }
            }
        }
        ns = ns_nxt;
    }
#pragma unroll
    for (int ct = 0; ct < CTILES; ++ct) {
        const int ch = (ct0 * CTILES + ct) * 32 + l31;
#pragma unroll
        for (int r = 0; r < 16; ++r) {
            const int row = (r & 3) + 8 * (r >> 2) + 4 * ksub;
            const int srow = wbase + row;
            if (srow < cntv) {
                if constexpr (EMODE == 0) {
                    outF[(size_t)srow * COUT + ch] = acc[ct][r];
                } else if constexpr (DENSE) {
                    const bool mk = (bal >> row) & 1;
                    o1[(size_t)srow * COUT + ch] =
                        mk ? (_Float16)bnr(acc[ct][r], sc1[ch], sh1[ch]) : (_Float16)0.f;
                    if constexpr (EMODE == 2)
                        o2[(size_t)srow * COUT + ch] =
                            mk ? (_Float16)bnr(acc[ct][r], sc2[ch], sh2[ch]) : (_Float16)0.f;
                } else {
                    o1[(size_t)srow * COUT + ch] =
                        (_Float16)bnr(acc[ct][r], sc1[ch], sh1[ch]);
                    if constexpr (EMODE == 2)
                        o2[(size_t)srow * COUT + ch] =
                            (_Float16)bnr(acc[ct][r], sc2[ch], sh2[ch]);
                }
            }
        }
    }
}

// 2x2x2 stride-2 down conv, dense coarse driver. CHILD_SPARSE: children via
// amap_f (L0 sparse); else children = dense fine idx. Output dense masked.
template<int KCH, int CTILES, int COUT, int SC, bool CHILD_SPARSE>
__global__ __launch_bounds__(64)
void dconv_m32(const h2* __restrict__ in, const h2* __restrict__ wb,
               const int* __restrict__ amap_f, const int* __restrict__ amap_cm,
               int capf, int nbx,
               _Float16* __restrict__ o1,
               const float* __restrict__ sc1, const float* __restrict__ sh1)
{
    constexpr int SF = SC * 2;
    constexpr int CTG = COUT / 32;
    constexpr int VC = SC * SC * SC;
    const int lane = threadIdx.x;
    const int sid = blockIdx.x;
    const int ct0 = sid / nbx;
    const int wbase = (sid - ct0 * nbx) * 32;
    if (wbase >= VC) return;
    const int l31 = lane & 31, ksub = lane >> 5;
    const int slot = wbase + l31;
    const bool on = slot < VC;
    int X = 0, Y = 0, Z = 0;
    if (on) { X = slot % SC; const int r = slot / SC; Y = r % SC; Z = r / SC; }
    const u64 bal = __ballot(on && amap_cm[on ? slot : 0] >= 0);

    auto calc_ns = [&](int t) -> int {
        int ns = capf;
        if (on) {
            const int fz = 2 * Z + ((t >> 2) & 1);
            const int fy = 2 * Y + ((t >> 1) & 1);
            const int fx = 2 * X + (t & 1);
            const int fi = (fz * SF + fy) * SF + fx;
            if constexpr (CHILD_SPARSE) {
                const int m = amap_f[fi];
                if (m >= 0) ns = m;
            } else {
                ns = fi;
            }
        }
        return ns;
    };

    f16v acc[CTILES];
#pragma unroll
    for (int c = 0; c < CTILES; ++c) acc[c] = (f16v)(0.f);
    int ns = calc_ns(0);
#pragma unroll 1
    for (int t = 0; t < 8; ++t) {
        const int ns_nxt = (t + 1 < 8) ? calc_ns(t + 1) : capf;
        const h2* __restrict__ wt =
            wb + ((size_t)t * CTG + ct0 * CTILES) * KCH * 256;
#pragma unroll
        for (int kc = 0; kc < KCH; ++kc) {
            const h8 a = *reinterpret_cast<const h8*>(
                in + (size_t)ns * (KCH * 8) + kc * 8 + ksub * 4);
#pragma unroll
            for (int ct = 0; ct < CTILES; ++ct) {
                const h8 b = *reinterpret_cast<const h8*>(
                    wt + ((size_t)ct * KCH + kc) * 256 + lane * 4);
                acc[ct] = __builtin_amdgcn_mfma_f32_32x32x16_f16(a, b, acc[ct], 0, 0, 0);
            }
        }
        ns = ns_nxt;
    }
#pragma unroll
    for (int ct = 0; ct < CTILES; ++ct) {
        const int ch = (ct0 * CTILES + ct) * 32 + l31;
#pragma unroll
        for (int r = 0; r < 16; ++r) {
            const int row = (r & 3) + 8 * (r >> 2) + 4 * ksub;
            const int srow = wbase + row;
            if (srow < VC) {
                const bool mk = (bal >> row) & 1;
                o1[(size_t)srow * COUT + ch] =
                    mk ? (_Float16)bnr(acc[ct][r], sc1[ch], sh1[ch]) : (_Float16)0.f;
            }
        }
    }
}

// Transpose conv 2x2x2 stride 2, dense coarse driver, A loaded once.
// CHILD_SPARSE: scatter to sparse L0 slots via amap_f (skip -1).
// Else: children = dense fine idx, masked by amap_cm (write 0 if inactive).
template<int KCH, int CTILES, int COUT, int SC, bool CHILD_SPARSE>
__global__ __launch_bounds__(64)
void uconv_m32(const h2* __restrict__ in, const h2* __restrict__ wb,
               const int* __restrict__ amap_f, const int* __restrict__ amap_cm,
               int capIn, int nbx,
               _Float16* __restrict__ out,
               const float* __restrict__ sc, const float* __restrict__ sh)
{
    constexpr int SF = SC * 2;
    constexpr int CTG = COUT / 32;
    constexpr int VC = SC * SC * SC;
    const int lane = threadIdx.x;
    const int sid = blockIdx.x;
    const int ct0 = sid / nbx;
    const int wbase = (sid - ct0 * nbx) * 32;
    if (wbase >= VC) return;
    const int l31 = lane & 31, ksub = lane >> 5;
    const int slot = wbase + l31;
    const bool on = slot < VC;
    int X = 0, Y = 0, Z = 0;
    if (on) { X = slot % SC; const int r = slot / SC; Y = r % SC; Z = r / SC; }

    h8 a[KCH];
    const int arow = on ? slot : capIn;
#pragma unroll
    for (int kc = 0; kc < KCH; ++kc)
        a[kc] = *reinterpret_cast<const h8*>(
            in + (size_t)arow * (KCH * 8) + kc * 8 + ksub * 4);

    auto calc_cs = [&](int t, bool& mk) -> int {
        int cs = -1;
        mk = false;
        if (on) {
            const int fz = 2 * Z + ((t >> 2) & 1);
            const int fy = 2 * Y + ((t >> 1) & 1);
            const int fx = 2 * X + (t & 1);
            const int fi = (fz * SF + fy) * SF + fx;
            if constexpr (CHILD_SPARSE) {
                cs = amap_f[fi];
                mk = cs >= 0;
            } else {
                cs = fi;
                mk = amap_cm[fi] >= 0;
            }
        }
        return cs;
    };

    bool mk;
    int cs = calc_cs(0, mk);
#pragma unroll 1
    for (int t = 0; t < 8; ++t) {
        bool mk_nxt = false;
        const int cs_nxt = (t + 1 < 8) ? calc_cs(t + 1, mk_nxt) : -1;
        const u64 balw = __ballot(on && (CHILD_SPARSE ? (cs >= 0) : true));
        const u64 balm = __ballot(mk);
        const h2* __restrict__ wt =
            wb + ((size_t)(7 - t) * CTG + ct0 * CTILES) * KCH * 256;
        f16v acc[CTILES];
#pragma unroll
        for (int c = 0; c < CTILES; ++c) acc[c] = (f16v)(0.f);
#pragma unroll
        for (int kc = 0; kc < KCH; ++kc) {
#pragma unroll
            for (int ct = 0; ct < CTILES; ++ct) {
                const h8 b = *reinterpret_cast<const h8*>(
                    wt + ((size_t)ct * KCH + kc) * 256 + lane * 4);
                acc[ct] = __builtin_amdgcn_mfma_f32_32x32x16_f16(a[kc], b, acc[ct], 0, 0, 0);
            }
        }
#pragma unroll
        for (int ct = 0; ct < CTILES; ++ct) {
            const int ch = (ct0 * CTILES + ct) * 32 + l31;
#pragma unroll
            for (int r = 0; r < 16; ++r) {
                const int row = (r & 3) + 8 * (r >> 2) + 4 * ksub;
                const int csr = __shfl(cs, row, 64);
                const bool wok = (balw >> row) & 1;
                const bool mrk = (balm >> row) & 1;
                if (wok)
                    out[(size_t)csr * COUT + ch] =
                        mrk ? (_Float16)bnr(acc[ct][r], sc[ch], sh[ch]) : (_Float16)0.f;
            }
        }
        cs = cs_nxt;
        mk = mk_nxt;
    }
}

// First conv: dense 1-channel grid -> 32ch sparse, fused bnA + f16 pack.
template<int S>
__global__ __launch_bounds__(128)
void cin_k(const float* __restrict__ grid, const float* __restrict__ w,
           const int* __restrict__ vlist, const int* __restrict__ cnt,
           _Float16* __restrict__ out, const float* __restrict__ sc,
           const float* __restrict__ sh)
{
    const int wOff = __builtin_amdgcn_readfirstlane(threadIdx.x >> 6) * 16;
    const int slot = blockIdx.x * 64 + (threadIdx.x & 63);
    if (slot >= *cnt) return;
    const int v = vlist[slot];
    const int x = v % S;
    const int rem = v / S;
    const int y = rem % S;
    const int z = rem / S;
    float acc[16];
#pragma unroll
    for (int c = 0; c < 16; ++c) acc[c] = 0.f;
#pragma unroll
    for (int t = 0; t < 27; ++t) {
        const int dz = t / 9 - 1, dy = (t / 3) % 3 - 1, dx = t % 3 - 1;
        const int nz = z + dz, ny = y + dy, nx = x + dx;
        if ((unsigned)nz >= (unsigned)S || (unsigned)ny >= (unsigned)S ||
            (unsigned)nx >= (unsigned)S) continue;
        const float val = grid[(nz * S + ny) * S + nx];
        const float* __restrict__ wp = w + t * 32 + wOff;
#pragma unroll
        for (int c = 0; c < 16; ++c) acc[c] = fmaf(val, wp[c], acc[c]);
    }
    union { float4 v[2]; _Float16 h[16]; } o;
#pragma unroll
    for (int c = 0; c < 16; ++c)
        o.h[c] = (_Float16)bnr(acc[c], sc[wOff + c], sh[wOff + c]);
    float4* dst = reinterpret_cast<float4*>(out + (size_t)slot * 32 + wOff);
    dst[0] = o.v[0];
    dst[1] = o.v[1];
}

// Final: bnrelu(y0, bnJ) then 32->3 linear per point.
__global__ __launch_bounds__(256)
void final_k(const int* __restrict__ coords, const float* __restrict__ y0,
             const int* __restrict__ amap0, const float* __restrict__ ssJ,
             const float* __restrict__ linW, const float* __restrict__ linb,
             int N, float* __restrict__ outp)
{
    const int n = blockIdx.x * blockDim.x + threadIdx.x;
    if (n >= N) return;
    const int i = coords[3 * n + 0];
    const int j = coords[3 * n + 1];
    const int k = coords[3 * n + 2];
    const int v = (i * NVOX + j) * NVOX + k;
    const int s = amap0[v];
    float a0 = linb[0], a1 = linb[1], a2 = linb[2];
    if (s >= 0) {
        const float* __restrict__ row = y0 + (size_t)s * 32;
#pragma unroll
        for (int c = 0; c < 32; ++c) {
            const float t = bnr(row[c], ssJ[c], ssJ[32 + c]);
            a0 = fmaf(t, linW[c * 3 + 0], a0);
            a1 = fmaf(t, linW[c * 3 + 1], a1);
            a2 = fmaf(t, linW[c * 3 + 2], a2);
        }
    }
    outp[3 * n + 0] = a0;
    outp[3 * n + 1] = a1;
    outp[3 * n + 2] = a2;
}

// Precompute per-channel scale/shift for all 10 BN layers.
__global__ void bn_prep(const float* __restrict__ A, const float* __restrict__ B,
                        const float* __restrict__ C, const float* __restrict__ D,
                        const float* __restrict__ E, const float* __restrict__ F,
                        const float* __restrict__ G, const float* __restrict__ H,
                        const float* __restrict__ I, const float* __restrict__ J,
                        float* __restrict__ ss)
{
    const float* bp[10] = {A, B, C, D, E, F, G, H, I, J};
    const int CH[10] = {32, 32, 64, 64, 96, 96, 128, 64, 64, 32};
    int idx = blockIdx.x * blockDim.x + threadIdx.x;
    if (idx >= 672) return;
    int l = 0, base = 0, off2 = 0;
    while (idx >= base + CH[l]) { base += CH[l]; off2 += 2 * CH[l]; ++l; }
    const int c = idx - base;
    const float* bn = bp[l];
    const int Cc = CH[l];
    const float g = bn[c], b = bn[Cc + c], mu = bn[2 * Cc + c], var = bn[3 * Cc + c];
    const float sc = g * rsqrtf(var + EPSB);
    ss[off2 + c] = sc;
    ss[off2 + Cc + c] = b - mu * sc;
}

__global__ __launch_bounds__(256)
void scatter_mark(const int* __restrict__ coords, const float* __restrict__ feats,
                  int N, float* __restrict__ grid, int* __restrict__ amap0)
{
    const int n = blockIdx.x * blockDim.x + threadIdx.x;
    if (n >= N) return;
    const int i = coords[3 * n + 0];
    const int j = coords[3 * n + 1];
    const int k = coords[3 * n + 2];
    const int v = (i * NVOX + j) * NVOX + k;
    atomicAdd(&grid[v], feats[n]);
    amap0[v] = -2;
}

// Coarse active flags: +1 if any fine child active, else -1.
template<int SC>
__global__ __launch_bounds__(256)
void flag_coarse(const int* __restrict__ amap_f, int* __restrict__ amap_c)
{
    constexpr int SF = SC * 2;
    const int v = blockIdx.x * blockDim.x + threadIdx.x;
    if (v >= SC * SC * SC) return;
    const int x = v % SC;
    const int rem = v / SC;
    const int y = rem % SC;
    const int z = rem / SC;
    bool any = false;
#pragma unroll
    for (int t = 0; t < 8; ++t) {
        const int fz = 2 * z + ((t >> 2) & 1);
        const int fy = 2 * y + ((t >> 1) & 1);
        const int fx = 2 * x + (t & 1);
        if (amap_f[(fz * SF + fy) * SF + fx] >= 0) any = true;
    }
    amap_c[v] = any ? 1 : -1;
}

// ---- deterministic raster-order compaction (L0 only) ----
__global__ __launch_bounds__(256)
void count_k(const int* __restrict__ flags, int V, int* __restrict__ counts)
{
    const int v = blockIdx.x * 256 + threadIdx.x;
    const bool act = (v < V) && (flags[v] == -2);
    const u64 m = __ballot(act);
    __shared__ int c[4];
    const int wid = threadIdx.x >> 6;
    if ((threadIdx.x & 63) == 0) c[wid] = __popcll(m);
    __syncthreads();
    if (threadIdx.x == 0) counts[blockIdx.x] = c[0] + c[1] + c[2] + c[3];
}

__global__ __launch_bounds__(1024)
void scan_k(int* __restrict__ counts, int nb, int* __restrict__ total)
{
    __shared__ int sums[1024];
    const int t = threadIdx.x;
    int v[4];
    int s = 0;
#pragma unroll
    for (int i = 0; i < 4; ++i) {
        const int idx = t * 4 + i;
        v[i] = (idx < nb) ? counts[idx] : 0;
        s += v[i];
    }
    sums[t] = s;
    __syncthreads();
    for (int d = 1; d < 1024; d <<= 1) {
        const int add = (t >= d) ? sums[t - d] : 0;
        __syncthreads();
        sums[t] += add;
        __syncthreads();
    }
    int base = (t > 0) ? sums[t - 1] : 0;
#pragma unroll
    for (int i = 0; i < 4; ++i) {
        const int idx = t * 4 + i;
        if (idx < nb) counts[idx] = base;
        base += v[i];
    }
    if (t == 1023) *total = sums[1023];
}

__global__ __launch_bounds__(256)
void emit_k(int* __restrict__ amap, int V, const int* __restrict__ offsets,
            int* __restrict__ vlist)
{
    const int v = blockIdx.x * 256 + threadIdx.x;
    const bool act = (v < V) && (amap[v] == -2);
    const u64 m = __ballot(act);
    __shared__ int wbase[4];
    const int wid = threadIdx.x >> 6;
    const int lane = threadIdx.x & 63;
    if (lane == 0) wbase[wid] = __popcll(m);
    __syncthreads();
    if (threadIdx.x == 0) {
        int s = 0;
#pragma unroll
        for (int i = 0; i < 4; ++i) { const int t = wbase[i]; wbase[i] = s; s += t; }
    }
    __syncthreads();
    if (act) {
        const int slot = offsets[blockIdx.x] + wbase[wid] +
                         __popcll(m & ((1ull << lane) - 1ull));
        amap[v] = slot;
        vlist[slot] = v;
    }
}

extern "C" void kernel_launch(void* const* d_in, const int* in_sizes, int n_in,
                              void* d_out, int out_size, void* d_ws, size_t ws_size,
                              hipStream_t stream) {
    const int*   coords = (const int*)d_in[0];
    const float* feats  = (const float*)d_in[1];
    const float* w_in   = (const float*)d_in[2];
    const float* w0a    = (const float*)d_in[3];
    const float* wdown0 = (const float*)d_in[4];
    const float* w1a    = (const float*)d_in[5];
    const float* wdown1 = (const float*)d_in[6];
    const float* w2     = (const float*)d_in[7];
    const float* wup1   = (const float*)d_in[8];
    const float* w1post = (const float*)d_in[9];
    const float* wup0   = (const float*)d_in[10];
    const float* w0post = (const float*)d_in[11];
    const float* linW = (const float*)d_in[22];
    const float* linb = (const float*)d_in[23];
    float* outp = (float*)d_out;

    const int N = in_sizes[1];            // 120000 points
    const int V0 = NVOX * NVOX * NVOX;
    const int V1 = 50 * 50 * 50;          // 125000
    const int V2 = 25 * 25 * 25;          // 15625
    const int cap0 = N;

    char* ws = (char*)d_ws;
    size_t off = 0;
    auto alloc = [&](size_t bytes) -> void* {
        void* p = ws + off;
        off += (bytes + 255) & ~(size_t)255;
        return p;
    };
    int*   amap0  = (int*)alloc((size_t)V0 * 4);
    int*   vlist0 = (int*)alloc((size_t)cap0 * 4);
    int*   amap1  = (int*)alloc((size_t)V1 * 4);   // dense active flags (+1/-1)
    int*   amap2  = (int*)alloc((size_t)V2 * 4);
    int*   cnt    = (int*)alloc(3 * 4);
    int*   counts = (int*)alloc(4096 * 4);
    float* ss     = (float*)alloc(1344 * 4);
    float* grid   = (float*)alloc((size_t)V0 * 4);
    // sparse L0 f16 acts (+1 zero row)
    _Float16* HA  = (_Float16*)alloc((size_t)(cap0 + 1) * 32 * 2);
    _Float16* HB  = (_Float16*)alloc((size_t)(cap0 + 1) * 32 * 2);
    _Float16* HI1 = (_Float16*)alloc((size_t)(cap0 + 1) * 32 * 2);
    _Float16* HI2 = (_Float16*)alloc((size_t)(cap0 + 1) * 32 * 2);
    // dense L1 f16 acts (+1 zero row)
    _Float16* HC  = (_Float16*)alloc((size_t)(V1 + 1) * 64 * 2);
    _Float16* HD  = (_Float16*)alloc((size_t)(V1 + 1) * 64 * 2);
    _Float16* HG1 = (_Float16*)alloc((size_t)(V1 + 1) * 64 * 2);
    _Float16* HG2 = (_Float16*)alloc((size_t)(V1 + 1) * 64 * 2);
    _Float16* HH  = (_Float16*)alloc((size_t)(V1 + 1) * 64 * 2);
    // dense L2 f16 acts (+1 zero row)
    _Float16* HE  = (_Float16*)alloc((size_t)(V2 + 1) * 96 * 2);
    _Float16* HF  = (_Float16*)alloc((size_t)(V2 + 1) * 96 * 2);
    float* y0f  = (float*)alloc((size_t)cap0 * 32 * 4);
    h2* wbA  = (h2*)alloc((size_t)27 * 1 * 2 * 256 * 4);
    h2* wb1  = (h2*)alloc((size_t)27 * 2 * 4 * 256 * 4);
    h2* wb2  = (h2*)alloc((size_t)27 * 3 * 6 * 256 * 4);
    h2* wbP1 = (h2*)alloc((size_t)27 * 2 * 8 * 256 * 4);
    h2* wbP0 = (h2*)alloc((size_t)27 * 1 * 4 * 256 * 4);
    h2* wbD0 = (h2*)alloc((size_t)8 * 2 * 2 * 256 * 4);
    h2* wbD1 = (h2*)alloc((size_t)8 * 3 * 4 * 256 * 4);
    h2* wbU1 = (h2*)alloc((size_t)8 * 2 * 6 * 256 * 4);
    h2* wbU0 = (h2*)alloc((size_t)8 * 1 * 4 * 256 * 4);
    if (off > ws_size) return;

    const int B = 256;
    const int gN  = (N + B - 1) / B;
    const int nb0 = (V0 + B - 1) / B;
    const int nb1 = (V1 + B - 1) / B;
    const int nb2 = (V2 + B - 1) / B;
    const int sb0 = (cap0 + 63) / 64;
    const int g1w_0 = (cap0 + 31) / 32;   // 3750 (sparse L0)
    const int gd1   = (V1 + 31) / 32;     // 3907 (dense L1)
    const int gd2   = (V2 + 31) / 32;     // 489  (dense L2)

    // ---- build phase ----
    hipMemsetAsync(amap0, 0xFF, (size_t)V0 * 4, stream);
    hipMemsetAsync(grid, 0, (size_t)V0 * 4, stream);
    hipMemsetAsync(HA + (size_t)cap0 * 32, 0, 64, stream);
    hipMemsetAsync(HB + (size_t)cap0 * 32, 0, 64, stream);
    hipMemsetAsync(HI1 + (size_t)cap0 * 32, 0, 64, stream);
    hipMemsetAsync(HI2 + (size_t)cap0 * 32, 0, 64, stream);
    hipMemsetAsync(HC + (size_t)V1 * 64, 0, 128, stream);
    hipMemsetAsync(HD + (size_t)V1 * 64, 0, 128, stream);
    hipMemsetAsync(HG1 + (size_t)V1 * 64, 0, 128, stream);
    hipMemsetAsync(HG2 + (size_t)V1 * 64, 0, 128, stream);
    hipMemsetAsync(HH + (size_t)V1 * 64, 0, 128, stream);
    hipMemsetAsync(HE + (size_t)V2 * 96, 0, 192, stream);
    hipMemsetAsync(HF + (size_t)V2 * 96, 0, 192, stream);
    bn_prep<<<3, 256, 0, stream>>>((const float*)d_in[12], (const float*)d_in[13],
                                   (const float*)d_in[14], (const float*)d_in[15],
                                   (const float*)d_in[16], (const float*)d_in[17],
                                   (const float*)d_in[18], (const float*)d_in[19],
                                   (const float*)d_in[20], (const float*)d_in[21], ss);
    prepB32<27, 32, 32><<<(27 * 1 * 2 * 256 + 255) / 256, 256, 0, stream>>>(w0a, wbA);
    prepB32<27, 64, 64><<<(27 * 2 * 4 * 256 + 255) / 256, 256, 0, stream>>>(w1a, wb1);
    prepB32<27, 96, 96><<<(27 * 3 * 6 * 256 + 255) / 256, 256, 0, stream>>>(w2, wb2);
    prepB32<27, 128, 64><<<(27 * 2 * 8 * 256 + 255) / 256, 256, 0, stream>>>(w1post, wbP1);
    prepB32<27, 64, 32><<<(27 * 1 * 4 * 256 + 255) / 256, 256, 0, stream>>>(w0post, wbP0);
    prepB32<8, 32, 64><<<(8 * 2 * 2 * 256 + 255) / 256, 256, 0, stream>>>(wdown0, wbD0);
    prepB32<8, 64, 96><<<(8 * 3 * 4 * 256 + 255) / 256, 256, 0, stream>>>(wdown1, wbD1);
    prepB32<8, 96, 64><<<(8 * 2 * 6 * 256 + 255) / 256, 256, 0, stream>>>(wup1, wbU1);
    prepB32<8, 64, 32><<<(8 * 1 * 4 * 256 + 255) / 256, 256, 0, stream>>>(wup0, wbU0);
    scatter_mark<<<gN, B, 0, stream>>>(coords, feats, N, grid, amap0);
    count_k<<<nb0, B, 0, stream>>>(amap0, V0, counts);
    scan_k<<<1, 1024, 0, stream>>>(counts, nb0, cnt + 0);
    emit_k<<<nb0, B, 0, stream>>>(amap0, V0, counts, vlist0);
    flag_coarse<50><<<nb1, B, 0, stream>>>(amap0, amap1);
    flag_coarse<25><<<nb2, B, 0, stream>>>(amap1, amap2);

    // ---- network ----
    cin_k<100><<<sb0, 128, 0, stream>>>(grid, w_in, vlist0, cnt + 0, HA,
                                        ss + 0, ss + 32);
    // x0 (sparse L0): -> HB (bnB), HI1 (bnI[0:32])
    gconv_m32<2, 0, 1, 32, 100, 2, false><<<g1w_0, 64, 0, stream>>>(
        (const h2*)HA, nullptr, wbA, amap0, vlist0, cnt + 0, cap0, g1w_0,
        nullptr, HB, ss + 64, ss + 96, HI1, ss + 1152, ss + 1216);
    // d0 (L0 sparse -> L1 dense): -> HC (bnC), masked by amap1
    dconv_m32<2, 2, 64, 50, true><<<gd1, 64, 0, stream>>>(
        (const h2*)HB, wbD0, amap0, amap1, cap0, gd1, HC, ss + 128, ss + 192);
    // x1 (dense L1): -> HD (bnD), HG1 (bnG[0:64])
    gconv_m32<4, 0, 2, 64, 50, 2, true><<<gd1, 64, 0, stream>>>(
        (const h2*)HC, nullptr, wb1, amap1, nullptr, nullptr, V1, gd1,
        nullptr, HD, ss + 256, ss + 320, HG1, ss + 768, ss + 896);
    // d1 (L1 dense -> L2 dense): -> HE (bnE), masked by amap2
    dconv_m32<4, 1, 96, 25, false><<<gd2 * 3, 64, 0, stream>>>(
        (const h2*)HD, wbD1, nullptr, amap2, V1, gd2, HE, ss + 384, ss + 480);
    // x2 (dense L2): -> HF (bnF)
    gconv_m32<6, 0, 1, 96, 25, 1, true><<<gd2 * 3, 64, 0, stream>>>(
        (const h2*)HE, nullptr, wb2, amap2, nullptr, nullptr, V2, gd2,
        nullptr, HF, ss + 576, ss + 672, nullptr, nullptr, nullptr);
    // u1 (L2 dense -> L1 dense): -> HG2 (bnG[64:128]), masked by amap1
    uconv_m32<6, 2, 64, 25, false><<<gd2, 64, 0, stream>>>(
        (const h2*)HF, wbU1, nullptr, amap1, V2, gd2,
        HG2, ss + 768 + 64, ss + 896 + 64);
    // y1 (dense L1, concat HG1|HG2): -> HH (bnH)
    gconv_m32<4, 4, 2, 64, 50, 1, true><<<gd1, 64, 0, stream>>>(
        (const h2*)HG1, (const h2*)HG2, wbP1, amap1, nullptr, nullptr, V1, gd1,
        nullptr, HH, ss + 1024, ss + 1088, nullptr, nullptr, nullptr);
    // u0 (L1 dense -> L0 sparse scatter): -> HI2 (bnI[32:64])
    uconv_m32<4, 1, 32, 50, true><<<gd1, 64, 0, stream>>>(
        (const h2*)HH, wbU0, amap0, nullptr, V1, gd1,
        HI2, ss + 1152 + 32, ss + 1216 + 32);
    // y0 (sparse L0, concat HI1|HI2): plain f32
    gconv_m32<2, 2, 1, 32, 100, 0, false><<<g1w_0, 64, 0, stream>>>(
        (const h2*)HI1, (const h2*)HI2, wbP0, amap0, vlist0, cnt + 0, cap0, g1w_0,
        y0f, nullptr, nullptr, nullptr, nullptr, nullptr, nullptr);
    final_k<<<gN, B, 0, stream>>>(coords, y0f, amap0, ss + 1280, linW, linb, N, outp);
}

// Round 20
// 447.437 us; speedup vs baseline: 1.2373x; 1.2373x over previous
//
#include <hip/hip_runtime.h>

// ---------------------------------------------------------------------------
// Sparse 3D U-Net forward (MI355X / gfx950).  [R18 best configuration]
// ALL convs (3x3x3, down 2x2x2, up-transpose 2x2x2) = barrier-free MFMA
// implicit GEMM (mfma_f32_32x32x16_f16), one wave per block, CTILES=2 where
// COUT>=64, natural block order. BN+ReLU(+f16) fused into producer epilogues.
// Up-conv: A-row loaded ONCE per wave (8 taps reuse it); child slot indices
// distributed across lanes via __shfl; scatter writes bnrelu'd f16.
// Acts [slot][cin] f16, zero row at cap; B pre-packed to fragment order.
// A: row=lane&31, k=(lane>>5)*8+j; B: col=lane&31, same k map.
// D: col=lane&31, row=(reg&3)+8*(reg>>2)+4*(lane>>5).
// ---------------------------------------------------------------------------

#define NVOX 100
#define EPSB 1e-4f
typedef unsigned long long u64;
typedef _Float16 h2 __attribute__((ext_vector_type(2)));
typedef _Float16 h8 __attribute__((ext_vector_type(8)));
typedef float f16v __attribute__((ext_vector_type(16)));
#define DEVFN __device__ __forceinline__

DEVFN float bnr(float v, float sc, float sh) { return fmaxf(fmaf(v, sc, sh), 0.f); }

// Packed B: wb[((t*CTG + ctg)*KCH + kc)*256 + lane*4 + jh] (h2 units):
//   k0 = kc*16 + (lane>>5)*8 + 2*jh ; co = ctg*32 + (lane&31)
template<int NTAPS, int CTOT, int COUT>
__global__ __launch_bounds__(256)
void prepB32(const float* __restrict__ w, h2* __restrict__ out)
{
    constexpr int CTG = COUT / 32, KCH = CTOT / 16;
    const int n = NTAPS * CTG * KCH * 256;
    const int idx = blockIdx.x * 256 + threadIdx.x;
    if (idx >= n) return;
    const int jh = idx & 3;
    const int lane = (idx >> 2) & 63;
    int r = idx >> 8;
    const int kc = r % KCH; r /= KCH;
    const int ct = r % CTG; const int t = r / CTG;
    const int k0 = kc * 16 + (lane >> 5) * 8 + 2 * jh;
    const int co = ct * 32 + (lane & 31);
    h2 v;
    v[0] = (_Float16)w[((size_t)t * CTOT + k0) * COUT + co];
    v[1] = (_Float16)w[((size_t)t * CTOT + k0 + 1) * COUT + co];
    out[idx] = v;
}

// EMODE: 0 = plain f32 out; 1 = bnrelu f16 out; 2 = two bnrelu f16 outs.
template<int EMODE, int COUT>
DEVFN void epilogue(float a, int srow, int ch,
                    float* outF, _Float16* o1, const float* sc1, const float* sh1,
                    _Float16* o2, const float* sc2, const float* sh2)
{
    if constexpr (EMODE == 0) {
        outF[(size_t)srow * COUT + ch] = a;
    } else {
        o1[(size_t)srow * COUT + ch] = (_Float16)bnr(a, sc1[ch], sh1[ch]);
        if constexpr (EMODE == 2)
            o2[(size_t)srow * COUT + ch] = (_Float16)bnr(a, sc2[ch], sh2[ch]);
    }
}

// 3x3x3 SAME submanifold conv, f16 acts, 32x32x16 MFMA, 1-wave blocks.
// 1D grid = nbx * (COUT/32/CTILES). block = 64.
template<int KC1, int KC2, int CTILES, int COUT, int S, int EMODE>
__global__ __launch_bounds__(64)
void gconv_m32(const h2* __restrict__ inA, const h2* __restrict__ inB,
               const h2* __restrict__ wb,
               const int* __restrict__ amap, const int* __restrict__ vlist,
               const int* __restrict__ cnt, int cap, int nbx,
               float* __restrict__ outF, _Float16* __restrict__ o1,
               const float* __restrict__ sc1, const float* __restrict__ sh1,
               _Float16* __restrict__ o2,
               const float* __restrict__ sc2, const float* __restrict__ sh2)
{
    constexpr int KCH = KC1 + KC2;
    constexpr int CTG = COUT / 32;
    const int lane = threadIdx.x;
    const int cntv = *cnt;
    const int sid = blockIdx.x;
    const int ct0 = sid / nbx;
    const int wbase = (sid - ct0 * nbx) * 32;
    if (wbase >= cntv) return;
    const int l31 = lane & 31, ksub = lane >> 5;
    const int slot = wbase + l31;
    const bool on = slot < cntv;
    int X = 0, Y = 0, Z = 0;
    if (on) { const int v = vlist[slot]; X = v % S; const int r = v / S; Y = r % S; Z = r / S; }

    auto calc_ns = [&](int t) -> int {
        int ns = cap;
        if (on) {
            const int dz = t / 9 - 1, dy = (t / 3) % 3 - 1, dx = t % 3 - 1;
            const int nz = Z + dz, ny = Y + dy, nx = X + dx;
            if ((unsigned)nz < (unsigned)S && (unsigned)ny < (unsigned)S &&
                (unsigned)nx < (unsigned)S) {
                const int m = amap[(nz * S + ny) * S + nx];
                if (m >= 0) ns = m;
            }
        }
        return ns;
    };

    f16v acc[CTILES];
#pragma unroll
    for (int c = 0; c < CTILES; ++c) acc[c] = (f16v)(0.f);
    int ns = calc_ns(0);
#pragma unroll 1
    for (int t = 0; t < 27; ++t) {
        const int ns_nxt = (t + 1 < 27) ? calc_ns(t + 1) : cap;
        const h2* __restrict__ wt =
            wb + ((size_t)t * CTG + ct0 * CTILES) * KCH * 256;
#pragma unroll
        for (int kc = 0; kc < KC1; ++kc) {
            const h8 a = *reinterpret_cast<const h8*>(
                inA + (size_t)ns * (KC1 * 8) + kc * 8 + ksub * 4);
#pragma unroll
            for (int ct = 0; ct < CTILES; ++ct) {
                const h8 b = *reinterpret_cast<const h8*>(
                    wt + ((size_t)ct * KCH + kc) * 256 + lane * 4);
                acc[ct] = __builtin_amdgcn_mfma_f32_32x32x16_f16(a, b, acc[ct], 0, 0, 0);
            }
        }
        if constexpr (KC2 > 0) {
#pragma unroll
            for (int kc = 0; kc < KC2; ++kc) {
                const h8 a = *reinterpret_cast<const h8*>(
                    inB + (size_t)ns * (KC2 * 8) + kc * 8 + ksub * 4);
#pragma unroll
                for (int ct = 0; ct < CTILES; ++ct) {
                    const h8 b = *reinterpret_cast<const h8*>(
                        wt + ((size_t)ct * KCH + KC1 + kc) * 256 + lane * 4);
                    acc[ct] = __builtin_amdgcn_mfma_f32_32x32x16_f16(a, b, acc[ct], 0, 0, 0);
                }
            }
        }
        ns = ns_nxt;
    }
#pragma unroll
    for (int ct = 0; ct < CTILES; ++ct) {
        const int ch = (ct0 * CTILES + ct) * 32 + l31;
#pragma unroll
        for (int r = 0; r < 16; ++r) {
            const int row = (r & 3) + 8 * (r >> 2) + 4 * ksub;
            const int srow = wbase + row;
            if (srow < cntv)
                epilogue<EMODE, COUT>(acc[ct][r], srow, ch, outF, o1, sc1, sh1,
                                      o2, sc2, sh2);
        }
    }
}

// 2x2x2 stride-2 down conv, coarse-driven, f16 acts, 1-wave, 1D grid.
template<int KCH, int CTILES, int COUT, int SC>
__global__ __launch_bounds__(64)
void dconv_m32(const h2* __restrict__ in, const h2* __restrict__ wb,
               const int* __restrict__ amap_f, const int* __restrict__ vlist_c,
               const int* __restrict__ cnt_c, int capf, int nbx,
               _Float16* __restrict__ o1,
               const float* __restrict__ sc1, const float* __restrict__ sh1)
{
    constexpr int SF = SC * 2;
    constexpr int CTG = COUT / 32;
    const int lane = threadIdx.x;
    const int cntv = *cnt_c;
    const int sid = blockIdx.x;
    const int ct0 = sid / nbx;
    const int wbase = (sid - ct0 * nbx) * 32;
    if (wbase >= cntv) return;
    const int l31 = lane & 31, ksub = lane >> 5;
    const int slot = wbase + l31;
    const bool on = slot < cntv;
    int X = 0, Y = 0, Z = 0;
    if (on) { const int v = vlist_c[slot]; X = v % SC; const int r = v / SC; Y = r % SC; Z = r / SC; }

    auto calc_ns = [&](int t) -> int {
        int ns = capf;
        if (on) {
            const int fz = 2 * Z + ((t >> 2) & 1);
            const int fy = 2 * Y + ((t >> 1) & 1);
            const int fx = 2 * X + (t & 1);
            const int m = amap_f[(fz * SF + fy) * SF + fx];
            if (m >= 0) ns = m;
        }
        return ns;
    };

    f16v acc[CTILES];
#pragma unroll
    for (int c = 0; c < CTILES; ++c) acc[c] = (f16v)(0.f);
    int ns = calc_ns(0);
#pragma unroll 1
    for (int t = 0; t < 8; ++t) {
        const int ns_nxt = (t + 1 < 8) ? calc_ns(t + 1) : capf;
        const h2* __restrict__ wt =
            wb + ((size_t)t * CTG + ct0 * CTILES) * KCH * 256;
#pragma unroll
        for (int kc = 0; kc < KCH; ++kc) {
            const h8 a = *reinterpret_cast<const h8*>(
                in + (size_t)ns * (KCH * 8) + kc * 8 + ksub * 4);
#pragma unroll
            for (int ct = 0; ct < CTILES; ++ct) {
                const h8 b = *reinterpret_cast<const h8*>(
                    wt + ((size_t)ct * KCH + kc) * 256 + lane * 4);
                acc[ct] = __builtin_amdgcn_mfma_f32_32x32x16_f16(a, b, acc[ct], 0, 0, 0);
            }
        }
        ns = ns_nxt;
    }
#pragma unroll
    for (int ct = 0; ct < CTILES; ++ct) {
        const int ch = (ct0 * CTILES + ct) * 32 + l31;
#pragma unroll
        for (int r = 0; r < 16; ++r) {
            const int row = (r & 3) + 8 * (r >> 2) + 4 * ksub;
            const int srow = wbase + row;
            if (srow < cntv)
                o1[(size_t)srow * COUT + ch] =
                    (_Float16)bnr(acc[ct][r], sc1[ch], sh1[ch]);
        }
    }
}

// Transpose conv 2x2x2 stride 2, coarse-driven, MFMA, 1-wave. A-row loaded
// once; child t uses weight tap 7-t; per-row child index via __shfl; scatter
// writes bnrelu'd f16.
template<int KCH, int CTILES, int COUT, int SC>
__global__ __launch_bounds__(64)
void uconv_m32(const h2* __restrict__ in, const h2* __restrict__ wb,
               const int* __restrict__ amap_f, const int* __restrict__ vlist_c,
               const int* __restrict__ cnt_c, int cap, int nbx,
               _Float16* __restrict__ out,
               const float* __restrict__ sc, const float* __restrict__ sh)
{
    constexpr int SF = SC * 2;
    constexpr int CTG = COUT / 32;
    const int lane = threadIdx.x;
    const int cntv = *cnt_c;
    const int sid = blockIdx.x;
    const int ct0 = sid / nbx;
    const int wbase = (sid - ct0 * nbx) * 32;
    if (wbase >= cntv) return;
    const int l31 = lane & 31, ksub = lane >> 5;
    const int slot = wbase + l31;
    const bool on = slot < cntv;
    int X = 0, Y = 0, Z = 0;
    if (on) { const int v = vlist_c[slot]; X = v % SC; const int r = v / SC; Y = r % SC; Z = r / SC; }

    // A rows: loaded once, reused by all 8 taps.
    h8 a[KCH];
    const int arow = on ? slot : cap;
#pragma unroll
    for (int kc = 0; kc < KCH; ++kc)
        a[kc] = *reinterpret_cast<const h8*>(
            in + (size_t)arow * (KCH * 8) + kc * 8 + ksub * 4);

    auto calc_cs = [&](int t) -> int {
        int cs = -1;
        if (on) {
            const int fz = 2 * Z + ((t >> 2) & 1);
            const int fy = 2 * Y + ((t >> 1) & 1);
            const int fx = 2 * X + (t & 1);
            cs = amap_f[(fz * SF + fy) * SF + fx];
        }
        return cs;
    };

    int cs = calc_cs(0);
#pragma unroll 1
    for (int t = 0; t < 8; ++t) {
        const int cs_nxt = (t + 1 < 8) ? calc_cs(t + 1) : -1;
        const h2* __restrict__ wt =
            wb + ((size_t)(7 - t) * CTG + ct0 * CTILES) * KCH * 256;
        f16v acc[CTILES];
#pragma unroll
        for (int c = 0; c < CTILES; ++c) acc[c] = (f16v)(0.f);
#pragma unroll
        for (int kc = 0; kc < KCH; ++kc) {
#pragma unroll
            for (int ct = 0; ct < CTILES; ++ct) {
                const h8 b = *reinterpret_cast<const h8*>(
                    wt + ((size_t)ct * KCH + kc) * 256 + lane * 4);
                acc[ct] = __builtin_amdgcn_mfma_f32_32x32x16_f16(a[kc], b, acc[ct], 0, 0, 0);
            }
        }
#pragma unroll
        for (int ct = 0; ct < CTILES; ++ct) {
            const int ch = (ct0 * CTILES + ct) * 32 + l31;
#pragma unroll
            for (int r = 0; r < 16; ++r) {
                const int row = (r & 3) + 8 * (r >> 2) + 4 * ksub;
                const int csr = __shfl(cs, row, 64);
                if (csr >= 0)
                    out[(size_t)csr * COUT + ch] =
                        (_Float16)bnr(acc[ct][r], sc[ch], sh[ch]);
            }
        }
        cs = cs_nxt;
    }
}

// First conv: dense 1-channel grid -> 32ch, fused bnA + f16 pack.
template<int S>
__global__ __launch_bounds__(128)
void cin_k(const float* __restrict__ grid, const float* __restrict__ w,
           const int* __restrict__ vlist, const int* __restrict__ cnt,
           _Float16* __restrict__ out, const float* __restrict__ sc,
           const float* __restrict__ sh)
{
    const int wOff = __builtin_amdgcn_readfirstlane(threadIdx.x >> 6) * 16;
    const int slot = blockIdx.x * 64 + (threadIdx.x & 63);
    if (slot >= *cnt) return;
    const int v = vlist[slot];
    const int x = v % S;
    const int rem = v / S;
    const int y = rem % S;
    const int z = rem / S;
    float acc[16];
#pragma unroll
    for (int c = 0; c < 16; ++c) acc[c] = 0.f;
#pragma unroll
    for (int t = 0; t < 27; ++t) {
        const int dz = t / 9 - 1, dy = (t / 3) % 3 - 1, dx = t % 3 - 1;
        const int nz = z + dz, ny = y + dy, nx = x + dx;
        if ((unsigned)nz >= (unsigned)S || (unsigned)ny >= (unsigned)S ||
            (unsigned)nx >= (unsigned)S) continue;
        const float val = grid[(nz * S + ny) * S + nx];
        const float* __restrict__ wp = w + t * 32 + wOff;
#pragma unroll
        for (int c = 0; c < 16; ++c) acc[c] = fmaf(val, wp[c], acc[c]);
    }
    union { float4 v[2]; _Float16 h[16]; } o;
#pragma unroll
    for (int c = 0; c < 16; ++c)
        o.h[c] = (_Float16)bnr(acc[c], sc[wOff + c], sh[wOff + c]);
    float4* dst = reinterpret_cast<float4*>(out + (size_t)slot * 32 + wOff);
    dst[0] = o.v[0];
    dst[1] = o.v[1];
}

// Final: bnrelu(y0, bnJ) then 32->3 linear per point.
__global__ __launch_bounds__(256)
void final_k(const int* __restrict__ coords, const float* __restrict__ y0,
             const int* __restrict__ amap0, const float* __restrict__ ssJ,
             const float* __restrict__ linW, const float* __restrict__ linb,
             int N, float* __restrict__ outp)
{
    const int n = blockIdx.x * blockDim.x + threadIdx.x;
    if (n >= N) return;
    const int i = coords[3 * n + 0];
    const int j = coords[3 * n + 1];
    const int k = coords[3 * n + 2];
    const int v = (i * NVOX + j) * NVOX + k;
    const int s = amap0[v];
    float a0 = linb[0], a1 = linb[1], a2 = linb[2];
    if (s >= 0) {
        const float* __restrict__ row = y0 + (size_t)s * 32;
#pragma unroll
        for (int c = 0; c < 32; ++c) {
            const float t = bnr(row[c], ssJ[c], ssJ[32 + c]);
            a0 = fmaf(t, linW[c * 3 + 0], a0);
            a1 = fmaf(t, linW[c * 3 + 1], a1);
            a2 = fmaf(t, linW[c * 3 + 2], a2);
        }
    }
    outp[3 * n + 0] = a0;
    outp[3 * n + 1] = a1;
    outp[3 * n + 2] = a2;
}

// Precompute per-channel scale/shift for all 10 BN layers.
__global__ void bn_prep(const float* __restrict__ A, const float* __restrict__ B,
                        const float* __restrict__ C, const float* __restrict__ D,
                        const float* __restrict__ E, const float* __restrict__ F,
                        const float* __restrict__ G, const float* __restrict__ H,
                        const float* __restrict__ I, const float* __restrict__ J,
                        float* __restrict__ ss)
{
    const float* bp[10] = {A, B, C, D, E, F, G, H, I, J};
    const int CH[10] = {32, 32, 64, 64, 96, 96, 128, 64, 64, 32};
    int idx = blockIdx.x * blockDim.x + threadIdx.x;
    if (idx >= 672) return;
    int l = 0, base = 0, off2 = 0;
    while (idx >= base + CH[l]) { base += CH[l]; off2 += 2 * CH[l]; ++l; }
    const int c = idx - base;
    const float* bn = bp[l];
    const int Cc = CH[l];
    const float g = bn[c], b = bn[Cc + c], mu = bn[2 * Cc + c], var = bn[3 * Cc + c];
    const float sc = g * rsqrtf(var + EPSB);
    ss[off2 + c] = sc;
    ss[off2 + Cc + c] = b - mu * sc;
}

__global__ __launch_bounds__(256)
void scatter_mark(const int* __restrict__ coords, const float* __restrict__ feats,
                  int N, float* __restrict__ grid, int* __restrict__ amap0)
{
    const int n = blockIdx.x * blockDim.x + threadIdx.x;
    if (n >= N) return;
    const int i = coords[3 * n + 0];
    const int j = coords[3 * n + 1];
    const int k = coords[3 * n + 2];
    const int v = (i * NVOX + j) * NVOX + k;
    atomicAdd(&grid[v], feats[n]);
    amap0[v] = -2;
}

template<int SC>
__global__ __launch_bounds__(256)
void flag_coarse(const int* __restrict__ amap_f, int* __restrict__ amap_c)
{
    constexpr int SF = SC * 2;
    const int v = blockIdx.x * blockDim.x + threadIdx.x;
    if (v >= SC * SC * SC) return;
    const int x = v % SC;
    const int rem = v / SC;
    const int y = rem % SC;
    const int z = rem / SC;
    bool any = false;
#pragma unroll
    for (int t = 0; t < 8; ++t) {
        const int fz = 2 * z + ((t >> 2) & 1);
        const int fy = 2 * y + ((t >> 1) & 1);
        const int fx = 2 * x + (t & 1);
        if (amap_f[(fz * SF + fy) * SF + fx] >= 0) any = true;
    }
    amap_c[v] = any ? -2 : -1;
}

// ---- deterministic raster-order compaction: count -> scan -> emit ----
__global__ __launch_bounds__(256)
void count_k(const int* __restrict__ flags, int V, int* __restrict__ counts)
{
    const int v = blockIdx.x * 256 + threadIdx.x;
    const bool act = (v < V) && (flags[v] == -2);
    const u64 m = __ballot(act);
    __shared__ int c[4];
    const int wid = threadIdx.x >> 6;
    if ((threadIdx.x & 63) == 0) c[wid] = __popcll(m);
    __syncthreads();
    if (threadIdx.x == 0) counts[blockIdx.x] = c[0] + c[1] + c[2] + c[3];
}

__global__ __launch_bounds__(1024)
void scan_k(int* __restrict__ counts, int nb, int* __restrict__ total)
{
    __shared__ int sums[1024];
    const int t = threadIdx.x;
    int v[4];
    int s = 0;
#pragma unroll
    for (int i = 0; i < 4; ++i) {
        const int idx = t * 4 + i;
        v[i] = (idx < nb) ? counts[idx] : 0;
        s += v[i];
    }
    sums[t] = s;
    __syncthreads();
    for (int d = 1; d < 1024; d <<= 1) {
        const int add = (t >= d) ? sums[t - d] : 0;
        __syncthreads();
        sums[t] += add;
        __syncthreads();
    }
    int base = (t > 0) ? sums[t - 1] : 0;
#pragma unroll
    for (int i = 0; i < 4; ++i) {
        const int idx = t * 4 + i;
        if (idx < nb) counts[idx] = base;
        base += v[i];
    }
    if (t == 1023) *total = sums[1023];
}

__global__ __launch_bounds__(256)
void emit_k(int* __restrict__ amap, int V, const int* __restrict__ offsets,
            int* __restrict__ vlist)
{
    const int v = blockIdx.x * 256 + threadIdx.x;
    const bool act = (v < V) && (amap[v] == -2);
    const u64 m = __ballot(act);
    __shared__ int wbase[4];
    const int wid = threadIdx.x >> 6;
    const int lane = threadIdx.x & 63;
    if (lane == 0) wbase[wid] = __popcll(m);
    __syncthreads();
    if (threadIdx.x == 0) {
        int s = 0;
#pragma unroll
        for (int i = 0; i < 4; ++i) { const int t = wbase[i]; wbase[i] = s; s += t; }
    }
    __syncthreads();
    if (act) {
        const int slot = offsets[blockIdx.x] + wbase[wid] +
                         __popcll(m & ((1ull << lane) - 1ull));
        amap[v] = slot;
        vlist[slot] = v;
    }
}

extern "C" void kernel_launch(void* const* d_in, const int* in_sizes, int n_in,
                              void* d_out, int out_size, void* d_ws, size_t ws_size,
                              hipStream_t stream) {
    const int*   coords = (const int*)d_in[0];
    const float* feats  = (const float*)d_in[1];
    const float* w_in   = (const float*)d_in[2];
    const float* w0a    = (const float*)d_in[3];
    const float* wdown0 = (const float*)d_in[4];
    const float* w1a    = (const float*)d_in[5];
    const float* wdown1 = (const float*)d_in[6];
    const float* w2     = (const float*)d_in[7];
    const float* wup1   = (const float*)d_in[8];
    const float* w1post = (const float*)d_in[9];
    const float* wup0   = (const float*)d_in[10];
    const float* w0post = (const float*)d_in[11];
    const float* linW = (const float*)d_in[22];
    const float* linb = (const float*)d_in[23];
    float* outp = (float*)d_out;

    const int N = in_sizes[1];            // 120000 points
    const int V0 = NVOX * NVOX * NVOX;
    const int V1 = 50 * 50 * 50;
    const int V2 = 25 * 25 * 25;
    const int cap0 = N;
    const int cap1 = 100000;
    const int cap2 = V2;

    char* ws = (char*)d_ws;
    size_t off = 0;
    auto alloc = [&](size_t bytes) -> void* {
        void* p = ws + off;
        off += (bytes + 255) & ~(size_t)255;
        return p;
    };
    int*   amap0  = (int*)alloc((size_t)V0 * 4);
    int*   vlist0 = (int*)alloc((size_t)cap0 * 4);
    int*   amap1  = (int*)alloc((size_t)V1 * 4);
    int*   vlist1 = (int*)alloc((size_t)cap1 * 4);
    int*   amap2  = (int*)alloc((size_t)V2 * 4);
    int*   vlist2 = (int*)alloc((size_t)cap2 * 4);
    int*   cnt    = (int*)alloc(3 * 4);
    int*   counts = (int*)alloc(4096 * 4);
    float* ss     = (float*)alloc(1344 * 4);
    float* grid   = (float*)alloc((size_t)V0 * 4);
    _Float16* HA  = (_Float16*)alloc((size_t)(cap0 + 1) * 32 * 2);
    _Float16* HB  = (_Float16*)alloc((size_t)(cap0 + 1) * 32 * 2);
    _Float16* HI1 = (_Float16*)alloc((size_t)(cap0 + 1) * 32 * 2);
    _Float16* HI2 = (_Float16*)alloc((size_t)(cap0 + 1) * 32 * 2);
    _Float16* HC  = (_Float16*)alloc((size_t)(cap1 + 1) * 64 * 2);
    _Float16* HD  = (_Float16*)alloc((size_t)(cap1 + 1) * 64 * 2);
    _Float16* HG1 = (_Float16*)alloc((size_t)(cap1 + 1) * 64 * 2);
    _Float16* HG2 = (_Float16*)alloc((size_t)(cap1 + 1) * 64 * 2);
    _Float16* HE  = (_Float16*)alloc((size_t)(cap2 + 1) * 96 * 2);
    _Float16* HF  = (_Float16*)alloc((size_t)(cap2 + 1) * 96 * 2);  // actF f16
    _Float16* HH  = (_Float16*)alloc((size_t)(cap1 + 1) * 64 * 2);  // actH f16
    float* y0f  = (float*)alloc((size_t)cap0 * 32 * 4);
    h2* wbA  = (h2*)alloc((size_t)27 * 1 * 2 * 256 * 4);
    h2* wb1  = (h2*)alloc((size_t)27 * 2 * 4 * 256 * 4);
    h2* wb2  = (h2*)alloc((size_t)27 * 3 * 6 * 256 * 4);
    h2* wbP1 = (h2*)alloc((size_t)27 * 2 * 8 * 256 * 4);
    h2* wbP0 = (h2*)alloc((size_t)27 * 1 * 4 * 256 * 4);
    h2* wbD0 = (h2*)alloc((size_t)8 * 2 * 2 * 256 * 4);
    h2* wbD1 = (h2*)alloc((size_t)8 * 3 * 4 * 256 * 4);
    h2* wbU1 = (h2*)alloc((size_t)8 * 2 * 6 * 256 * 4);   // wup1: CTOT=96, COUT=64
    h2* wbU0 = (h2*)alloc((size_t)8 * 1 * 4 * 256 * 4);   // wup0: CTOT=64, COUT=32
    if (off > ws_size) return;

    const int B = 256;
    const int gN  = (N + B - 1) / B;
    const int nb0 = (V0 + B - 1) / B;
    const int nb1 = (V1 + B - 1) / B;
    const int nb2 = (V2 + B - 1) / B;
    const int sb0 = (cap0 + 63) / 64;
    const int g1w_0 = (cap0 + 31) / 32;   // 3750
    const int g1w_1 = (cap1 + 31) / 32;   // 3125
    const int g1w_2 = (cap2 + 31) / 32;   // 489

    // ---- build phase ----
    hipMemsetAsync(amap0, 0xFF, (size_t)V0 * 4, stream);
    hipMemsetAsync(grid, 0, (size_t)V0 * 4, stream);
    hipMemsetAsync(HA + (size_t)cap0 * 32, 0, 64, stream);
    hipMemsetAsync(HB + (size_t)cap0 * 32, 0, 64, stream);
    hipMemsetAsync(HI1 + (size_t)cap0 * 32, 0, 64, stream);
    hipMemsetAsync(HI2 + (size_t)cap0 * 32, 0, 64, stream);
    hipMemsetAsync(HC + (size_t)cap1 * 64, 0, 128, stream);
    hipMemsetAsync(HD + (size_t)cap1 * 64, 0, 128, stream);
    hipMemsetAsync(HG1 + (size_t)cap1 * 64, 0, 128, stream);
    hipMemsetAsync(HG2 + (size_t)cap1 * 64, 0, 128, stream);
    hipMemsetAsync(HE + (size_t)cap2 * 96, 0, 192, stream);
    hipMemsetAsync(HF + (size_t)cap2 * 96, 0, 192, stream);
    hipMemsetAsync(HH + (size_t)cap1 * 64, 0, 128, stream);
    bn_prep<<<3, 256, 0, stream>>>((const float*)d_in[12], (const float*)d_in[13],
                                   (const float*)d_in[14], (const float*)d_in[15],
                                   (const float*)d_in[16], (const float*)d_in[17],
                                   (const float*)d_in[18], (const float*)d_in[19],
                                   (const float*)d_in[20], (const float*)d_in[21], ss);
    prepB32<27, 32, 32><<<(27 * 1 * 2 * 256 + 255) / 256, 256, 0, stream>>>(w0a, wbA);
    prepB32<27, 64, 64><<<(27 * 2 * 4 * 256 + 255) / 256, 256, 0, stream>>>(w1a, wb1);
    prepB32<27, 96, 96><<<(27 * 3 * 6 * 256 + 255) / 256, 256, 0, stream>>>(w2, wb2);
    prepB32<27, 128, 64><<<(27 * 2 * 8 * 256 + 255) / 256, 256, 0, stream>>>(w1post, wbP1);
    prepB32<27, 64, 32><<<(27 * 1 * 4 * 256 + 255) / 256, 256, 0, stream>>>(w0post, wbP0);
    prepB32<8, 32, 64><<<(8 * 2 * 2 * 256 + 255) / 256, 256, 0, stream>>>(wdown0, wbD0);
    prepB32<8, 64, 96><<<(8 * 3 * 4 * 256 + 255) / 256, 256, 0, stream>>>(wdown1, wbD1);
    prepB32<8, 96, 64><<<(8 * 2 * 6 * 256 + 255) / 256, 256, 0, stream>>>(wup1, wbU1);
    prepB32<8, 64, 32><<<(8 * 1 * 4 * 256 + 255) / 256, 256, 0, stream>>>(wup0, wbU0);
    scatter_mark<<<gN, B, 0, stream>>>(coords, feats, N, grid, amap0);
    count_k<<<nb0, B, 0, stream>>>(amap0, V0, counts);
    scan_k<<<1, 1024, 0, stream>>>(counts, nb0, cnt + 0);
    emit_k<<<nb0, B, 0, stream>>>(amap0, V0, counts, vlist0);
    flag_coarse<50><<<nb1, B, 0, stream>>>(amap0, amap1);
    count_k<<<nb1, B, 0, stream>>>(amap1, V1, counts);
    scan_k<<<1, 1024, 0, stream>>>(counts, nb1, cnt + 1);
    emit_k<<<nb1, B, 0, stream>>>(amap1, V1, counts, vlist1);
    flag_coarse<25><<<nb2, B, 0, stream>>>(amap1, amap2);
    count_k<<<nb2, B, 0, stream>>>(amap2, V2, counts);
    scan_k<<<1, 1024, 0, stream>>>(counts, nb2, cnt + 2);
    emit_k<<<nb2, B, 0, stream>>>(amap2, V2, counts, vlist2);

    // ---- network (bnrelu fused into producer epilogues; 1D natural grids) --
    cin_k<100><<<sb0, 128, 0, stream>>>(grid, w_in, vlist0, cnt + 0, HA,
                                        ss + 0, ss + 32);
    // x0 = conv(HA): -> HB (bnB), HI1 (bnI[0:32])
    gconv_m32<2, 0, 1, 32, 100, 2><<<g1w_0, 64, 0, stream>>>(
        (const h2*)HA, nullptr, wbA, amap0, vlist0, cnt + 0, cap0, g1w_0,
        nullptr, HB, ss + 64, ss + 96, HI1, ss + 1152, ss + 1216);
    // d0 = down(HB): -> HC (bnC)
    dconv_m32<2, 2, 64, 50><<<g1w_1, 64, 0, stream>>>(
        (const h2*)HB, wbD0, amap0, vlist1, cnt + 1, cap0, g1w_1,
        HC, ss + 128, ss + 192);
    // x1 = conv(HC): -> HD (bnD), HG1 (bnG[0:64])
    gconv_m32<4, 0, 2, 64, 50, 2><<<g1w_1, 64, 0, stream>>>(
        (const h2*)HC, nullptr, wb1, amap1, vlist1, cnt + 1, cap1, g1w_1,
        nullptr, HD, ss + 256, ss + 320, HG1, ss + 768, ss + 896);
    // d1 = down(HD): -> HE (bnE)
    dconv_m32<4, 1, 96, 25><<<g1w_2 * 3, 64, 0, stream>>>(
        (const h2*)HD, wbD1, amap1, vlist2, cnt + 2, cap1, g1w_2,
        HE, ss + 384, ss + 480);
    // x2 = conv(HE): -> HF f16 (bnF)
    gconv_m32<6, 0, 1, 96, 25, 1><<<g1w_2 * 3, 64, 0, stream>>>(
        (const h2*)HE, nullptr, wb2, amap2, vlist2, cnt + 2, cap2, g1w_2,
        nullptr, HF, ss + 576, ss + 672, nullptr, nullptr, nullptr);
    // u1 = up(HF): -> HG2 (bnG[64:128]); A loaded once per wave
    uconv_m32<6, 2, 64, 25><<<g1w_2, 64, 0, stream>>>(
        (const h2*)HF, wbU1, amap1, vlist2, cnt + 2, cap2, g1w_2,
        HG2, ss + 768 + 64, ss + 896 + 64);
    // y1 = conv(HG1|HG2): -> HH f16 (bnH)
    gconv_m32<4, 4, 2, 64, 50, 1><<<g1w_1, 64, 0, stream>>>(
        (const h2*)HG1, (const h2*)HG2, wbP1, amap1, vlist1, cnt + 1, cap1, g1w_1,
        nullptr, HH, ss + 1024, ss + 1088, nullptr, nullptr, nullptr);
    // u0 = up(HH): -> HI2 (bnI[32:64])
    uconv_m32<4, 1, 32, 50><<<g1w_1, 64, 0, stream>>>(
        (const h2*)HH, wbU0, amap0, vlist1, cnt + 1, cap1, g1w_1,
        HI2, ss + 1152 + 32, ss + 1216 + 32);
    // y0 = conv(HI1|HI2): plain f32
    gconv_m32<2, 2, 1, 32, 100, 0><<<g1w_0, 64, 0, stream>>>(
        (const h2*)HI1, (const h2*)HI2, wbP0, amap0, vlist0, cnt + 0, cap0, g1w_0,
        y0f, nullptr, nullptr, nullptr, nullptr, nullptr, nullptr);
    final_k<<<gN, B, 0, stream>>>(coords, y0f, amap0, ss + 1280, linW, linb, N, outp);
}